// Round 4
// baseline (1017.716 us; speedup 1.0000x reference)
//
#include <hip/hip_runtime.h>

#define NN 10000
#define DF 128
#define NE 640000
#define NBINS 64
#define NGB ((NN + NBINS - 1) / NBINS)   // 157
#define QCAP 8192
#define NOENT 0xFFFFFFFFu

__device__ __forceinline__ unsigned int f2bf(float f) {
    unsigned int u = __float_as_uint(f);
    u = (u + 0x7FFFu + ((u >> 16) & 1u)) >> 16;   // round-to-nearest-even
    return u;
}
__device__ __forceinline__ float bf_lo(unsigned int v) { return __uint_as_float(v << 16); }
__device__ __forceinline__ float bf_hi(unsigned int v) { return __uint_as_float(v & 0xFFFF0000u); }

// ---------------------------------------------------------------------------
// P1: pack feat to bf16, feature pairing (l, l+64) per uint so the gather's
// LDS adds are bank-conflict-free (agg[de*128+lane] -> bank = lane%32).
// ---------------------------------------------------------------------------
__global__ __launch_bounds__(256) void pack_feat(const float* __restrict__ feat,
                                                 unsigned int* __restrict__ feat_bf)
{
    const int id = blockIdx.x * 256 + threadIdx.x;   // NN*64 total
    if (id >= NN * 64) return;
    const int row = id >> 6, l = id & 63;
    const float a = feat[row * DF + l];
    const float c = feat[row * DF + l + 64];
    feat_bf[id] = f2bf(a) | (f2bf(c) << 16);
}

// ---------------------------------------------------------------------------
// P2: fold src_fc into fc:  wprod = Wfc[:,128:] @ W_src   [128][128],
//     bsrc2[o] = dot(Wfc[o,128:], b_src).
// Block = one output row o; 128 threads over k. W_src col reads coalesced.
// ---------------------------------------------------------------------------
__global__ __launch_bounds__(128) void prep_w(const float* __restrict__ Wfc,
                                              const float* __restrict__ Wsrc,
                                              const float* __restrict__ bsrc,
                                              float* __restrict__ wprod,
                                              float* __restrict__ bsrc2)
{
    const int o = blockIdx.x;
    const int k = threadIdx.x;
    const float* w2 = Wfc + (size_t)o * 256 + 128;   // uniform -> scalar loads
    float acc = 0.f;
#pragma unroll 8
    for (int j = 0; j < 128; ++j)
        acc = fmaf(w2[j], Wsrc[j * 128 + k], acc);
    wprod[o * 128 + k] = acc;

    float p = w2[k] * bsrc[k];
#pragma unroll
    for (int d = 32; d > 0; d >>= 1) p += __shfl_down(p, d);
    __shared__ float red[2];
    if ((k & 63) == 0) red[k >> 6] = p;
    __syncthreads();
    if (k == 0) bsrc2[o] = red[0] + red[1];
}

// ---------------------------------------------------------------------------
// G: fused grouping + gather-mean. Block owns dst range [lo, lo+64).
// Pass A: scan ALL edges (dst is 2.56MB, L2-resident); queue matched
//         (de,src) pairs in LDS. Pass B: waves drain queue 4-deep,
//         accumulate feat_bf rows into LDS agg with ds_add_f32.
// Writes neigh (mean) + deg once, coalesced. No global atomics.
// ---------------------------------------------------------------------------
__global__ __launch_bounds__(512) void gather_feat(const unsigned int* __restrict__ feat_bf,
                                                   const int* __restrict__ srcv,
                                                   const int* __restrict__ dstv,
                                                   float* __restrict__ neigh,
                                                   int* __restrict__ deg_g)
{
    __shared__ float agg[NBINS * 128];          // 32 KB
    __shared__ unsigned int queue[QCAP + 32];   // 32.1 KB
    __shared__ int degs[NBINS];
    __shared__ int ncur;

    const int tid = threadIdx.x;
    const int lo = blockIdx.x * NBINS;
    const unsigned span = (unsigned)(min(lo + NBINS, NN) - lo);

    for (int i = tid; i < NBINS * 128; i += 512) agg[i] = 0.f;
    if (tid < NBINS) degs[tid] = 0;
    if (tid == 0) ncur = 0;
    __syncthreads();

    // ---- Pass A: scan edge list (int2 = 2 edges/thread/iter, 625 iters) ----
    const int2* d2 = (const int2*)dstv;
#pragma unroll 4
    for (int it = 0; it < NE / (512 * 2); ++it) {
        const int idx = tid + 512 * it;
        const int2 dd = d2[idx];
        const unsigned r0 = (unsigned)(dd.x - lo);
        const unsigned r1 = (unsigned)(dd.y - lo);
        if (r0 < span) {
            const int p = atomicAdd(&ncur, 1);
            const int s = srcv[2 * idx];
            if (p < QCAP) queue[p] = (r0 << 24) | (unsigned)s;
            atomicAdd(&degs[r0], 1);
        }
        if (r1 < span) {
            const int p = atomicAdd(&ncur, 1);
            const int s = srcv[2 * idx + 1];
            if (p < QCAP) queue[p] = (r1 << 24) | (unsigned)s;
            atomicAdd(&degs[r1], 1);
        }
    }
    __syncthreads();
    const int nq = min(ncur, QCAP);
    const int nqp = (nq + 31) & ~31;
    if (tid < nqp - nq) queue[nq + tid] = NOENT;
    __syncthreads();

    // ---- Pass B: 8 waves, 4 entries deep (independent loads -> MLP) ----
    const int wave = tid >> 6, lane = tid & 63;
    for (int q0 = wave * 4; q0 < nqp; q0 += 32) {
        const unsigned e0 = queue[q0 + 0];
        const unsigned e1 = queue[q0 + 1];
        const unsigned e2 = queue[q0 + 2];
        const unsigned e3 = queue[q0 + 3];
        unsigned w0 = 0, w1 = 0, w2 = 0, w3 = 0;
        if (e0 != NOENT) w0 = feat_bf[(size_t)(e0 & 0xFFFFFFu) * 64 + lane];
        if (e1 != NOENT) w1 = feat_bf[(size_t)(e1 & 0xFFFFFFu) * 64 + lane];
        if (e2 != NOENT) w2 = feat_bf[(size_t)(e2 & 0xFFFFFFu) * 64 + lane];
        if (e3 != NOENT) w3 = feat_bf[(size_t)(e3 & 0xFFFFFFu) * 64 + lane];
        if (e0 != NOENT) {
            atomicAdd(&agg[(e0 >> 24) * 128 + lane], bf_lo(w0));
            atomicAdd(&agg[(e0 >> 24) * 128 + 64 + lane], bf_hi(w0));
        }
        if (e1 != NOENT) {
            atomicAdd(&agg[(e1 >> 24) * 128 + lane], bf_lo(w1));
            atomicAdd(&agg[(e1 >> 24) * 128 + 64 + lane], bf_hi(w1));
        }
        if (e2 != NOENT) {
            atomicAdd(&agg[(e2 >> 24) * 128 + lane], bf_lo(w2));
            atomicAdd(&agg[(e2 >> 24) * 128 + 64 + lane], bf_hi(w2));
        }
        if (e3 != NOENT) {
            atomicAdd(&agg[(e3 >> 24) * 128 + lane], bf_lo(w3));
            atomicAdd(&agg[(e3 >> 24) * 128 + 64 + lane], bf_hi(w3));
        }
    }
    __syncthreads();

    // ---- finalize: neigh = agg/deg (0 if deg==0), coalesced writes ----
    for (int i = tid; i < NBINS * 128; i += 512) {
        const int bin = i >> 7;
        const int v = lo + bin;
        if (v < NN) {
            const float dg = (float)degs[bin];
            const float inv = dg > 0.f ? 1.f / dg : 0.f;
            neigh[(size_t)v * DF + (i & 127)] = agg[i] * inv;
        }
    }
    if (tid < NBINS && lo + tid < NN) deg_g[lo + tid] = degs[tid];
}

// ---------------------------------------------------------------------------
// A: out = feat @ Wfc1^T + neigh @ wprod^T + b_fc + [deg>0]*bsrc2
// Block owns 64 rows x 64 out-cols (blockIdx.y = col half). Wt in LDS stride
// 65 (conflict-free). 8 waves x 8 rows/wave -> 32 FMA : 4 ds_read per step.
// ---------------------------------------------------------------------------
__global__ __launch_bounds__(512) void apply_fc(const float* __restrict__ feat,
                                                const float* __restrict__ neigh,
                                                const int* __restrict__ deg,
                                                const float* __restrict__ Wfc,
                                                const float* __restrict__ wprod,
                                                const float* __restrict__ bfc,
                                                const float* __restrict__ bsrc2,
                                                float* __restrict__ out)
{
    __shared__ float Wt[256 * 65];   // 66.6 KB -> 2 blocks/CU
    const int tid = threadIdx.x;
    const int oh = blockIdx.y;       // 0 or 1

    for (int i = tid; i < 64 * 256; i += 512) {
        const int oc = i >> 8, j = i & 255;
        const int o = oh * 64 + oc;
        const float v = (j < 128) ? Wfc[(size_t)o * 256 + j]
                                  : wprod[(size_t)o * 128 + (j - 128)];
        Wt[j * 65 + oc] = v;         // consecutive j -> consecutive banks
    }
    __syncthreads();

    const int wave = tid >> 6, lane = tid & 63;
    const int row0 = blockIdx.x * 64 + wave * 8;
    const float b0 = bfc[oh * 64 + lane];
    const float b1 = bsrc2[oh * 64 + lane];

    float acc[8];
#pragma unroll
    for (int r = 0; r < 8; ++r) {
        const int row = min(row0 + r, NN - 1);
        acc[r] = b0 + (deg[row] > 0 ? b1 : 0.0f);
    }

    for (int k4 = 0; k4 < 32; ++k4) {
        const float w0 = Wt[(4 * k4 + 0) * 65 + lane];
        const float w1 = Wt[(4 * k4 + 1) * 65 + lane];
        const float w2 = Wt[(4 * k4 + 2) * 65 + lane];
        const float w3 = Wt[(4 * k4 + 3) * 65 + lane];
#pragma unroll
        for (int r = 0; r < 8; ++r) {
            const int row = min(row0 + r, NN - 1);
            const float4 f = *(const float4*)(feat + (size_t)row * DF + k4 * 4);
            acc[r] += f.x * w0 + f.y * w1 + f.z * w2 + f.w * w3;
        }
    }
    for (int k4 = 0; k4 < 32; ++k4) {
        const float w0 = Wt[(128 + 4 * k4 + 0) * 65 + lane];
        const float w1 = Wt[(128 + 4 * k4 + 1) * 65 + lane];
        const float w2 = Wt[(128 + 4 * k4 + 2) * 65 + lane];
        const float w3 = Wt[(128 + 4 * k4 + 3) * 65 + lane];
#pragma unroll
        for (int r = 0; r < 8; ++r) {
            const int row = min(row0 + r, NN - 1);
            const float4 f = *(const float4*)(neigh + (size_t)row * DF + k4 * 4);
            acc[r] += f.x * w0 + f.y * w1 + f.z * w2 + f.w * w3;
        }
    }
#pragma unroll
    for (int r = 0; r < 8; ++r) {
        const int row = row0 + r;
        if (row < NN) out[(size_t)row * DF + oh * 64 + lane] = acc[r];
    }
}

extern "C" void kernel_launch(void* const* d_in, const int* in_sizes, int n_in,
                              void* d_out, int out_size, void* d_ws, size_t ws_size,
                              hipStream_t stream) {
    const float* feat  = (const float*)d_in[0];   // [NN, 128]
    const float* W_src = (const float*)d_in[1];   // [128, 128]
    const float* b_src = (const float*)d_in[2];   // [128]
    const float* W_fc  = (const float*)d_in[3];   // [128, 256]
    const float* b_fc  = (const float*)d_in[4];   // [128]
    const int*   src   = (const int*)d_in[5];     // [NE]
    const int*   dst   = (const int*)d_in[6];     // [NE]
    float* out = (float*)d_out;

    // ws: feat_bf [NN*64 u32] | neigh [NN*128 f32] | deg [NN i32] |
    //     wprod [128*128 f32] | bsrc2 [128 f32]
    unsigned int* feat_bf = (unsigned int*)d_ws;
    float* neigh = (float*)(feat_bf + (size_t)NN * 64);
    int*   deg   = (int*)(neigh + (size_t)NN * DF);
    float* wprod = (float*)(deg + NN);
    float* bsrc2 = wprod + 128 * 128;

    pack_feat  <<<(NN * 64 + 255) / 256, 256, 0, stream>>>(feat, feat_bf);
    prep_w     <<<128, 128, 0, stream>>>(W_fc, W_src, b_src, wprod, bsrc2);
    gather_feat<<<NGB, 512, 0, stream>>>(feat_bf, src, dst, neigh, deg);
    apply_fc   <<<dim3(NGB, 2), 512, 0, stream>>>(feat, neigh, deg, W_fc, wprod,
                                                  b_fc, bsrc2, out);
}

// Round 7
// 804.451 us; speedup vs baseline: 1.2651x; 1.2651x over previous
//
#include <hip/hip_runtime.h>

#define NN 10000
#define DF 128
#define NE 640000
#define NBUCK 313                 // ceil(NN/32) buckets of 32 dst nodes
#define TILE 8192
#define NTILES ((NE + TILE - 1) / TILE)   // 79
#define EPT 8                     // edges per thread in binning (1024 thr)

__device__ __forceinline__ unsigned int f2bf(float f) {
    unsigned int u = __float_as_uint(f);
    u = (u + 0x7FFFu + ((u >> 16) & 1u)) >> 16;   // RNE
    return u;
}
__device__ __forceinline__ float bf_lo(unsigned int v) { return __uint_as_float(v << 16); }
__device__ __forceinline__ float bf_hi(unsigned int v) { return __uint_as_float(v & 0xFFFF0000u); }

// ---------------------------------------------------------------------------
// P1: pack feat to bf16 pairs (l, l+64) per u32 (conflict-free gather adds).
// ---------------------------------------------------------------------------
__global__ __launch_bounds__(256) void pack_feat(const float* __restrict__ feat,
                                                 unsigned int* __restrict__ feat_bf)
{
    const int id = blockIdx.x * 256 + threadIdx.x;
    if (id >= NN * 64) return;
    const int row = id >> 6, l = id & 63;
    feat_bf[id] = f2bf(feat[row * DF + l]) | (f2bf(feat[row * DF + l + 64]) << 16);
}

// ---------------------------------------------------------------------------
// P2: fold src_fc into fc: wprod = Wfc[:,128:] @ W_src, bsrc2 = Wfc2 . b_src
// ---------------------------------------------------------------------------
__global__ __launch_bounds__(128) void prep_w(const float* __restrict__ Wfc,
                                              const float* __restrict__ Wsrc,
                                              const float* __restrict__ bsrc,
                                              float* __restrict__ wprod,
                                              float* __restrict__ bsrc2)
{
    const int o = blockIdx.x;
    const int k = threadIdx.x;
    const float* w2 = Wfc + (size_t)o * 256 + 128;   // uniform -> scalar loads
    float acc = 0.f;
#pragma unroll 8
    for (int j = 0; j < 128; ++j)
        acc = fmaf(w2[j], Wsrc[j * 128 + k], acc);
    wprod[o * 128 + k] = acc;

    float p = w2[k] * bsrc[k];
#pragma unroll
    for (int d = 32; d > 0; d >>= 1) p += __shfl_down(p, d);
    __shared__ float red[2];
    if ((k & 63) == 0) red[k >> 6] = p;
    __syncthreads();
    if (k == 0) bsrc2[o] = red[0] + red[1];
}

// ---------------------------------------------------------------------------
// B1: per-(tile,bucket) histogram -> tbl[b*NTILES + t]. Fully overwritten
// every call (no zero-init dependency, no global atomics).
// ---------------------------------------------------------------------------
__global__ __launch_bounds__(1024) void hist2(const int* __restrict__ dstv,
                                              int* __restrict__ tbl)
{
    __shared__ int h[NBUCK];
    const int tid = threadIdx.x;
    if (tid < NBUCK) h[tid] = 0;
    __syncthreads();
    const int e0 = blockIdx.x * TILE;
#pragma unroll
    for (int j = 0; j < EPT; ++j) {
        const int e = e0 + j * 1024 + tid;
        if (e < NE) atomicAdd(&h[dstv[e] >> 5], 1);
    }
    __syncthreads();
    if (tid < NBUCK) tbl[tid * NTILES + blockIdx.x] = h[tid];
}

// ---------------------------------------------------------------------------
// B2: in-place transform tbl counts -> per-tile global bases:
//     tbl[b][t] = off[b] + sum_{t'<t} h[b][t'];  off[b] = bucket prefix.
// Single block, thread b owns row b (contiguous row scan). Deterministic.
// ---------------------------------------------------------------------------
__global__ __launch_bounds__(512) void scan2(int* __restrict__ tbl,
                                             int* __restrict__ off)
{
    __shared__ int sc[512];
    const int b = threadIdx.x;
    int tot = 0;
    if (b < NBUCK) {
        for (int t = 0; t < NTILES; ++t) {
            const int c = tbl[b * NTILES + t];
            tbl[b * NTILES + t] = tot;
            tot += c;
        }
    }
    sc[b] = (b < NBUCK) ? tot : 0;
    __syncthreads();
    for (int d = 1; d < 512; d <<= 1) {
        int x = (b >= d) ? sc[b - d] : 0;
        __syncthreads();
        sc[b] += x;
        __syncthreads();
    }
    if (b < NBUCK) {
        const int base = (b == 0) ? 0 : sc[b - 1];
        off[b] = base;
        for (int t = 0; t < NTILES; ++t) tbl[b * NTILES + t] += base;
    }
    if (b == NBUCK - 1) off[NBUCK] = sc[b];
}

// ---------------------------------------------------------------------------
// B3: LDS-staged binning with PRECOMPUTED bases (zero global atomics,
// deterministic layout). entry = (dst<<14)|src (28 bits; both < 2^14).
// ---------------------------------------------------------------------------
__global__ __launch_bounds__(1024) void bin2(const int* __restrict__ srcv,
                                             const int* __restrict__ dstv,
                                             const int* __restrict__ tbl,
                                             unsigned int* __restrict__ ents)
{
    __shared__ unsigned int ent[TILE];   // 32 KB
    __shared__ int h[NBUCK];
    __shared__ int lbase[NBUCK];
    __shared__ int lcur[NBUCK];
    __shared__ int gbase[NBUCK];
    __shared__ int sc[1024];

    const int tid = threadIdx.x;
    const int bx = blockIdx.x;
    const int e0 = bx * TILE;
    const int n = min(TILE, NE - e0);

    int myd[EPT], mys[EPT];
#pragma unroll
    for (int j = 0; j < EPT; ++j) {
        const int e = e0 + j * 1024 + tid;
        if (e < NE) { myd[j] = dstv[e]; mys[j] = srcv[e]; }
        else { myd[j] = -1; mys[j] = 0; }
    }

    if (tid < NBUCK) {
        h[tid] = 0; lcur[tid] = 0;
        gbase[tid] = tbl[tid * NTILES + bx];   // deterministic global base
    }
    __syncthreads();
#pragma unroll
    for (int j = 0; j < EPT; ++j)
        if (myd[j] >= 0) atomicAdd(&h[myd[j] >> 5], 1);
    __syncthreads();

    // block-wide inclusive scan of h -> exclusive lbase
    sc[tid] = (tid < NBUCK) ? h[tid] : 0;
    __syncthreads();
    for (int d = 1; d < 1024; d <<= 1) {
        int x = (tid >= d) ? sc[tid - d] : 0;
        __syncthreads();
        sc[tid] += x;
        __syncthreads();
    }
    if (tid < NBUCK) lbase[tid] = (tid == 0) ? 0 : sc[tid - 1];
    __syncthreads();

    // local scatter into bucket-sorted LDS order (LDS atomics only)
#pragma unroll
    for (int j = 0; j < EPT; ++j) {
        if (myd[j] >= 0) {
            const int b = myd[j] >> 5;
            const int p = atomicAdd(&lcur[b], 1);
            ent[lbase[b] + p] = ((unsigned)myd[j] << 14) | (unsigned)mys[j];
        }
    }
    __syncthreads();

    // coalesced flush into disjoint precomputed global runs
    for (int i = tid; i < n; i += 1024) {
        const unsigned u = ent[i];
        const int b = (int)(u >> 19);        // dst>>5
        ents[gbase[b] + (i - lbase[b])] = u;
    }
}

// ---------------------------------------------------------------------------
// G: one block per bucket (32 dst nodes). 8 waves drain entries 4-deep,
// accumulate feat_bf rows into LDS agg via ds_add (conflict-free), write
// neigh (mean) + deg once, coalesced. Src index clamped (OOB insurance).
// ---------------------------------------------------------------------------
__global__ __launch_bounds__(512) void gather_feat(const unsigned int* __restrict__ feat_bf,
                                                   const unsigned int* __restrict__ ents,
                                                   const int* __restrict__ off,
                                                   float* __restrict__ neigh,
                                                   int* __restrict__ deg_g)
{
    __shared__ float agg[32 * 128];   // 16 KB
    __shared__ int degs[32];

    const int tid = threadIdx.x;
    const int b = blockIdx.x;
    const int lo = b * 32;
    const int r0 = off[b], r1 = off[b + 1];

    for (int i = tid; i < 32 * 128; i += 512) agg[i] = 0.f;
    if (tid < 32) degs[tid] = 0;
    __syncthreads();

    const int wave = tid >> 6, lane = tid & 63;
    for (int q0 = r0 + wave * 4; q0 < r1; q0 += 32) {
        unsigned e0 = (q0 + 0 < r1) ? ents[q0 + 0] : 0xFFFFFFFFu;
        unsigned e1 = (q0 + 1 < r1) ? ents[q0 + 1] : 0xFFFFFFFFu;
        unsigned e2 = (q0 + 2 < r1) ? ents[q0 + 2] : 0xFFFFFFFFu;
        unsigned e3 = (q0 + 3 < r1) ? ents[q0 + 3] : 0xFFFFFFFFu;
        unsigned w0 = 0, w1 = 0, w2 = 0, w3 = 0;
        if (e0 != 0xFFFFFFFFu) w0 = feat_bf[(size_t)min(e0 & 0x3FFFu, (unsigned)(NN - 1)) * 64 + lane];
        if (e1 != 0xFFFFFFFFu) w1 = feat_bf[(size_t)min(e1 & 0x3FFFu, (unsigned)(NN - 1)) * 64 + lane];
        if (e2 != 0xFFFFFFFFu) w2 = feat_bf[(size_t)min(e2 & 0x3FFFu, (unsigned)(NN - 1)) * 64 + lane];
        if (e3 != 0xFFFFFFFFu) w3 = feat_bf[(size_t)min(e3 & 0x3FFFu, (unsigned)(NN - 1)) * 64 + lane];
        if (e0 != 0xFFFFFFFFu) {
            const int dl = (int)((e0 >> 14) & 31u);
            atomicAdd(&agg[dl * 128 + lane], bf_lo(w0));
            atomicAdd(&agg[dl * 128 + 64 + lane], bf_hi(w0));
            if (lane == 0) atomicAdd(&degs[dl], 1);
        }
        if (e1 != 0xFFFFFFFFu) {
            const int dl = (int)((e1 >> 14) & 31u);
            atomicAdd(&agg[dl * 128 + lane], bf_lo(w1));
            atomicAdd(&agg[dl * 128 + 64 + lane], bf_hi(w1));
            if (lane == 0) atomicAdd(&degs[dl], 1);
        }
        if (e2 != 0xFFFFFFFFu) {
            const int dl = (int)((e2 >> 14) & 31u);
            atomicAdd(&agg[dl * 128 + lane], bf_lo(w2));
            atomicAdd(&agg[dl * 128 + 64 + lane], bf_hi(w2));
            if (lane == 0) atomicAdd(&degs[dl], 1);
        }
        if (e3 != 0xFFFFFFFFu) {
            const int dl = (int)((e3 >> 14) & 31u);
            atomicAdd(&agg[dl * 128 + lane], bf_lo(w3));
            atomicAdd(&agg[dl * 128 + 64 + lane], bf_hi(w3));
            if (lane == 0) atomicAdd(&degs[dl], 1);
        }
    }
    __syncthreads();

    for (int i = tid; i < 32 * 128; i += 512) {
        const int bin = i >> 7;
        const int v = lo + bin;
        if (v < NN) {
            const float dg = (float)degs[bin];
            const float inv = dg > 0.f ? 1.f / dg : 0.f;
            neigh[(size_t)v * DF + (i & 127)] = agg[i] * inv;
        }
    }
    if (tid < 32 && lo + tid < NN) deg_g[lo + tid] = degs[tid];
}

// ---------------------------------------------------------------------------
// A: out = feat @ Wfc1^T + neigh @ wprod^T + b_fc + [deg>0]*bsrc2
// 64 rows x 64 out-cols per block; Wt LDS stride 65; 8 rows/wave.
// ---------------------------------------------------------------------------
__global__ __launch_bounds__(512) void apply_fc(const float* __restrict__ feat,
                                                const float* __restrict__ neigh,
                                                const int* __restrict__ deg,
                                                const float* __restrict__ Wfc,
                                                const float* __restrict__ wprod,
                                                const float* __restrict__ bfc,
                                                const float* __restrict__ bsrc2,
                                                float* __restrict__ out)
{
    __shared__ float Wt[256 * 65];   // 66.6 KB
    const int tid = threadIdx.x;
    const int oh = blockIdx.y;

    for (int i = tid; i < 64 * 256; i += 512) {
        const int oc = i >> 8, j = i & 255;
        const int o = oh * 64 + oc;
        const float v = (j < 128) ? Wfc[(size_t)o * 256 + j]
                                  : wprod[(size_t)o * 128 + (j - 128)];
        Wt[j * 65 + oc] = v;
    }
    __syncthreads();

    const int wave = tid >> 6, lane = tid & 63;
    const int row0 = blockIdx.x * 64 + wave * 8;
    const float b0 = bfc[oh * 64 + lane];
    const float b1 = bsrc2[oh * 64 + lane];

    float acc[8];
#pragma unroll
    for (int r = 0; r < 8; ++r) {
        const int row = min(row0 + r, NN - 1);
        acc[r] = b0 + (deg[row] > 0 ? b1 : 0.0f);
    }

    for (int k4 = 0; k4 < 32; ++k4) {
        const float w0 = Wt[(4 * k4 + 0) * 65 + lane];
        const float w1 = Wt[(4 * k4 + 1) * 65 + lane];
        const float w2 = Wt[(4 * k4 + 2) * 65 + lane];
        const float w3 = Wt[(4 * k4 + 3) * 65 + lane];
#pragma unroll
        for (int r = 0; r < 8; ++r) {
            const int row = min(row0 + r, NN - 1);
            const float4 f = *(const float4*)(feat + (size_t)row * DF + k4 * 4);
            acc[r] += f.x * w0 + f.y * w1 + f.z * w2 + f.w * w3;
        }
    }
    for (int k4 = 0; k4 < 32; ++k4) {
        const float w0 = Wt[(128 + 4 * k4 + 0) * 65 + lane];
        const float w1 = Wt[(128 + 4 * k4 + 1) * 65 + lane];
        const float w2 = Wt[(128 + 4 * k4 + 2) * 65 + lane];
        const float w3 = Wt[(128 + 4 * k4 + 3) * 65 + lane];
#pragma unroll
        for (int r = 0; r < 8; ++r) {
            const int row = min(row0 + r, NN - 1);
            const float4 f = *(const float4*)(neigh + (size_t)row * DF + k4 * 4);
            acc[r] += f.x * w0 + f.y * w1 + f.z * w2 + f.w * w3;
        }
    }
#pragma unroll
    for (int r = 0; r < 8; ++r) {
        const int row = row0 + r;
        if (row < NN) out[(size_t)row * DF + oh * 64 + lane] = acc[r];
    }
}

extern "C" void kernel_launch(void* const* d_in, const int* in_sizes, int n_in,
                              void* d_out, int out_size, void* d_ws, size_t ws_size,
                              hipStream_t stream) {
    const float* feat  = (const float*)d_in[0];
    const float* W_src = (const float*)d_in[1];
    const float* b_src = (const float*)d_in[2];
    const float* W_fc  = (const float*)d_in[3];
    const float* b_fc  = (const float*)d_in[4];
    const int*   src   = (const int*)d_in[5];
    const int*   dst   = (const int*)d_in[6];
    float* out = (float*)d_out;

    // ws: feat_bf [NN*64 u32] | neigh [NN*128 f32] | deg [NN] | wprod [128*128] |
    //     bsrc2 [128] | off [NBUCK+1] | tbl [NBUCK*NTILES] | ents [NE u32]
    unsigned int* feat_bf = (unsigned int*)d_ws;
    float* neigh = (float*)(feat_bf + (size_t)NN * 64);
    int*   deg   = (int*)(neigh + (size_t)NN * DF);
    float* wprod = (float*)(deg + NN);
    float* bsrc2 = wprod + 128 * 128;
    int*   off   = (int*)(bsrc2 + 128);
    int*   tbl   = off + (NBUCK + 1);
    unsigned int* ents = (unsigned int*)(tbl + NBUCK * NTILES);

    pack_feat  <<<(NN * 64 + 255) / 256, 256, 0, stream>>>(feat, feat_bf);
    prep_w     <<<128, 128, 0, stream>>>(W_fc, W_src, b_src, wprod, bsrc2);
    hist2      <<<NTILES, 1024, 0, stream>>>(dst, tbl);
    scan2      <<<1, 512, 0, stream>>>(tbl, off);
    bin2       <<<NTILES, 1024, 0, stream>>>(src, dst, tbl, ents);
    gather_feat<<<NBUCK, 512, 0, stream>>>(feat_bf, ents, off, neigh, deg);
    apply_fc   <<<dim3((NN + 63) / 64, 2), 512, 0, stream>>>(feat, neigh, deg, W_fc,
                                                             wprod, b_fc, bsrc2, out);
}

// Round 8
// 128.894 us; speedup vs baseline: 7.8958x; 6.2412x over previous
//
#include <hip/hip_runtime.h>

#define NN 10000
#define DF 128
#define NE 640000
#define GBN 16                    // nodes per bucket
#define NBUCK 625                 // NN/16
#define TILE 8192
#define NTILES ((NE + TILE - 1) / TILE)   // 79
#define EPT 8                     // edges/thread in hist/bin (1024 thr)
#define GCAP 2048                 // bucket entry capacity (E[cnt]=1024, sd~32)

__device__ __forceinline__ unsigned int f2bf(float f) {
    unsigned int u = __float_as_uint(f);
    u = (u + 0x7FFFu + ((u >> 16) & 1u)) >> 16;   // RNE
    return u;
}
__device__ __forceinline__ float bf_lo(unsigned int v) { return __uint_as_float(v << 16); }
__device__ __forceinline__ float bf_hi(unsigned int v) { return __uint_as_float(v & 0xFFFF0000u); }

// ---------------------------------------------------------------------------
// P1: pack feat to bf16 pairs (l, l+64) per u32.
// ---------------------------------------------------------------------------
__global__ __launch_bounds__(256) void pack_feat(const float* __restrict__ feat,
                                                 unsigned int* __restrict__ feat_bf)
{
    const int id = blockIdx.x * 256 + threadIdx.x;
    if (id >= NN * 64) return;
    const int row = id >> 6, l = id & 63;
    feat_bf[id] = f2bf(feat[row * DF + l]) | (f2bf(feat[row * DF + l + 64]) << 16);
}

// ---------------------------------------------------------------------------
// P2: fold src_fc into fc: wprod = Wfc[:,128:] @ W_src, bsrc2 = Wfc2 . b_src
// ---------------------------------------------------------------------------
__global__ __launch_bounds__(128) void prep_w(const float* __restrict__ Wfc,
                                              const float* __restrict__ Wsrc,
                                              const float* __restrict__ bsrc,
                                              float* __restrict__ wprod,
                                              float* __restrict__ bsrc2)
{
    const int o = blockIdx.x;
    const int k = threadIdx.x;
    const float* w2 = Wfc + (size_t)o * 256 + 128;   // uniform -> scalar loads
    float acc = 0.f;
#pragma unroll 8
    for (int j = 0; j < 128; ++j)
        acc = fmaf(w2[j], Wsrc[j * 128 + k], acc);
    wprod[o * 128 + k] = acc;

    float p = w2[k] * bsrc[k];
#pragma unroll
    for (int d = 32; d > 0; d >>= 1) p += __shfl_down(p, d);
    __shared__ float red[2];
    if ((k & 63) == 0) red[k >> 6] = p;
    __syncthreads();
    if (k == 0) bsrc2[o] = red[0] + red[1];
}

// ---------------------------------------------------------------------------
// B1: per-(tile,bucket) histogram -> tbl[t*NBUCK + b]  (coalesced writes).
// Fully overwritten every call; no global atomics.
// ---------------------------------------------------------------------------
__global__ __launch_bounds__(1024) void hist2(const int* __restrict__ dstv,
                                              int* __restrict__ tbl)
{
    __shared__ int h[NBUCK];
    const int tid = threadIdx.x;
    if (tid < NBUCK) h[tid] = 0;
    __syncthreads();
    const int e0 = blockIdx.x * TILE;
#pragma unroll
    for (int j = 0; j < EPT; ++j) {
        const int e = e0 + j * 1024 + tid;
        if (e < NE) atomicAdd(&h[dstv[e] >> 4], 1);
    }
    __syncthreads();
    if (tid < NBUCK) tbl[blockIdx.x * NBUCK + tid] = h[tid];
}

// ---------------------------------------------------------------------------
// B2: in-place: tbl[t][b] = off[b] + sum_{t'<t} h[t'][b]. Column scan is
// coalesced across threads (thread b walks tbl[t*NBUCK+b]). Deterministic.
// ---------------------------------------------------------------------------
__global__ __launch_bounds__(1024) void scan2(int* __restrict__ tbl,
                                              int* __restrict__ off)
{
    __shared__ int sc[1024];
    const int b = threadIdx.x;
    int tot = 0;
    if (b < NBUCK) {
        for (int t = 0; t < NTILES; ++t) {
            const int c = tbl[t * NBUCK + b];
            tbl[t * NBUCK + b] = tot;
            tot += c;
        }
    }
    sc[b] = (b < NBUCK) ? tot : 0;
    __syncthreads();
    for (int d = 1; d < 1024; d <<= 1) {
        int x = (b >= d) ? sc[b - d] : 0;
        __syncthreads();
        sc[b] += x;
        __syncthreads();
    }
    if (b < NBUCK) {
        const int base = (b == 0) ? 0 : sc[b - 1];
        off[b] = base;
        for (int t = 0; t < NTILES; ++t) tbl[t * NBUCK + b] += base;
    }
    if (b == NBUCK - 1) off[NBUCK] = sc[b];
}

// ---------------------------------------------------------------------------
// B3: LDS-staged binning with PRECOMPUTED bases (no global atomics,
// deterministic, replay-safe). entry = (dst<<14)|src; bucket = entry>>18.
// ---------------------------------------------------------------------------
__global__ __launch_bounds__(1024) void bin2(const int* __restrict__ srcv,
                                             const int* __restrict__ dstv,
                                             const int* __restrict__ tbl,
                                             unsigned int* __restrict__ ents)
{
    __shared__ unsigned int ent[TILE];   // 32 KB
    __shared__ int h[NBUCK];
    __shared__ int lbase[NBUCK];
    __shared__ int lcur[NBUCK];
    __shared__ int gbase[NBUCK];
    __shared__ int sc[1024];

    const int tid = threadIdx.x;
    const int bx = blockIdx.x;
    const int e0 = bx * TILE;
    const int n = min(TILE, NE - e0);

    int myd[EPT], mys[EPT];
#pragma unroll
    for (int j = 0; j < EPT; ++j) {
        const int e = e0 + j * 1024 + tid;
        if (e < NE) { myd[j] = dstv[e]; mys[j] = srcv[e]; }
        else { myd[j] = -1; mys[j] = 0; }
    }

    if (tid < NBUCK) {
        h[tid] = 0; lcur[tid] = 0;
        gbase[tid] = tbl[bx * NBUCK + tid];   // deterministic global base
    }
    __syncthreads();
#pragma unroll
    for (int j = 0; j < EPT; ++j)
        if (myd[j] >= 0) atomicAdd(&h[myd[j] >> 4], 1);
    __syncthreads();

    sc[tid] = (tid < NBUCK) ? h[tid] : 0;
    __syncthreads();
    for (int d = 1; d < 1024; d <<= 1) {
        int x = (tid >= d) ? sc[tid - d] : 0;
        __syncthreads();
        sc[tid] += x;
        __syncthreads();
    }
    if (tid < NBUCK) lbase[tid] = (tid == 0) ? 0 : sc[tid - 1];
    __syncthreads();

    // local scatter into bucket-sorted LDS order (int LDS atomics only)
#pragma unroll
    for (int j = 0; j < EPT; ++j) {
        if (myd[j] >= 0) {
            const int b = myd[j] >> 4;
            const int p = atomicAdd(&lcur[b], 1);
            ent[lbase[b] + p] = ((unsigned)myd[j] << 14) | (unsigned)mys[j];
        }
    }
    __syncthreads();

    // coalesced flush into disjoint precomputed global runs
    for (int i = tid; i < n; i += 1024) {
        const unsigned u = ent[i];
        const int b = (int)(u >> 18);        // dst>>4
        ents[gbase[b] + (i - lbase[b])] = u;
    }
}

// ---------------------------------------------------------------------------
// G v2: one block per 16-node bucket. Counting-sort entries by local dst in
// LDS (int atomics only), then 4 waves x 4 nodes: stream each node's run
// with REGISTER accumulation, 4-deep independent 256B gathers. Zero f32
// atomics. One coalesced neigh write per node.
// ---------------------------------------------------------------------------
__global__ __launch_bounds__(256) void gather_feat(const unsigned int* __restrict__ feat_bf,
                                                   const unsigned int* __restrict__ ents,
                                                   const int* __restrict__ off,
                                                   float* __restrict__ neigh,
                                                   int* __restrict__ deg_g)
{
    __shared__ unsigned int raw[GCAP];       // 8 KB
    __shared__ unsigned short sorted[GCAP];  // 4 KB (src ids, 14 bits)
    __shared__ int h[GBN], base[GBN], cur[GBN];

    const int tid = threadIdx.x;
    const int b = blockIdx.x;
    const int lo = b * GBN;
    const int r0 = off[b], r1 = off[b + 1];
    const int cnt = min(r1 - r0, GCAP);

    if (tid < GBN) { h[tid] = 0; cur[tid] = 0; }
    __syncthreads();
    for (int i = tid; i < cnt; i += 256) {
        const unsigned u = ents[r0 + i];
        raw[i] = u;
        atomicAdd(&h[(u >> 14) & (GBN - 1)], 1);
    }
    __syncthreads();
    if (tid == 0) {
        int s = 0;
#pragma unroll
        for (int j = 0; j < GBN; ++j) { base[j] = s; s += h[j]; }
    }
    __syncthreads();
    for (int i = tid; i < cnt; i += 256) {
        const unsigned u = raw[i];
        const int dl = (int)((u >> 14) & (GBN - 1));
        const int p = base[dl] + atomicAdd(&cur[dl], 1);
        sorted[p] = (unsigned short)(u & 0x3FFFu);
    }
    __syncthreads();

    const int wave = tid >> 6, lane = tid & 63;
#pragma unroll
    for (int j = 0; j < 4; ++j) {
        const int dl = wave * 4 + j;
        const int s0 = base[dl], n = h[dl];
        float ax = 0.f, ay = 0.f;
        int i = 0;
        for (; i + 4 <= n; i += 4) {
            const int ia = sorted[s0 + i + 0];
            const int ib = sorted[s0 + i + 1];
            const int ic = sorted[s0 + i + 2];
            const int id = sorted[s0 + i + 3];
            const unsigned a  = feat_bf[(size_t)ia * 64 + lane];
            const unsigned bb = feat_bf[(size_t)ib * 64 + lane];
            const unsigned c  = feat_bf[(size_t)ic * 64 + lane];
            const unsigned d  = feat_bf[(size_t)id * 64 + lane];
            ax += (bf_lo(a) + bf_lo(bb)) + (bf_lo(c) + bf_lo(d));
            ay += (bf_hi(a) + bf_hi(bb)) + (bf_hi(c) + bf_hi(d));
        }
        for (; i < n; ++i) {
            const unsigned a = feat_bf[(size_t)sorted[s0 + i] * 64 + lane];
            ax += bf_lo(a); ay += bf_hi(a);
        }
        const int v = lo + dl;
        const float inv = (n > 0) ? 1.f / (float)n : 0.f;
        if (v < NN) {
            neigh[(size_t)v * DF + lane]      = ax * inv;
            neigh[(size_t)v * DF + 64 + lane] = ay * inv;
            if (lane == 0) deg_g[v] = n;
        }
    }
}

// ---------------------------------------------------------------------------
// A: out = feat @ Wfc1^T + neigh @ wprod^T + b_fc + [deg>0]*bsrc2
// 64 rows x 64 out-cols per block; Wt LDS stride 65; 8 rows/wave.
// ---------------------------------------------------------------------------
__global__ __launch_bounds__(512) void apply_fc(const float* __restrict__ feat,
                                                const float* __restrict__ neigh,
                                                const int* __restrict__ deg,
                                                const float* __restrict__ Wfc,
                                                const float* __restrict__ wprod,
                                                const float* __restrict__ bfc,
                                                const float* __restrict__ bsrc2,
                                                float* __restrict__ out)
{
    __shared__ float Wt[256 * 65];   // 66.6 KB
    const int tid = threadIdx.x;
    const int oh = blockIdx.y;

    for (int i = tid; i < 64 * 256; i += 512) {
        const int oc = i >> 8, j = i & 255;
        const int o = oh * 64 + oc;
        const float v = (j < 128) ? Wfc[(size_t)o * 256 + j]
                                  : wprod[(size_t)o * 128 + (j - 128)];
        Wt[j * 65 + oc] = v;
    }
    __syncthreads();

    const int wave = tid >> 6, lane = tid & 63;
    const int row0 = blockIdx.x * 64 + wave * 8;
    const float b0 = bfc[oh * 64 + lane];
    const float b1 = bsrc2[oh * 64 + lane];

    float acc[8];
#pragma unroll
    for (int r = 0; r < 8; ++r) {
        const int row = min(row0 + r, NN - 1);
        acc[r] = b0 + (deg[row] > 0 ? b1 : 0.0f);
    }

    for (int k4 = 0; k4 < 32; ++k4) {
        const float w0 = Wt[(4 * k4 + 0) * 65 + lane];
        const float w1 = Wt[(4 * k4 + 1) * 65 + lane];
        const float w2 = Wt[(4 * k4 + 2) * 65 + lane];
        const float w3 = Wt[(4 * k4 + 3) * 65 + lane];
#pragma unroll
        for (int r = 0; r < 8; ++r) {
            const int row = min(row0 + r, NN - 1);
            const float4 f = *(const float4*)(feat + (size_t)row * DF + k4 * 4);
            acc[r] += f.x * w0 + f.y * w1 + f.z * w2 + f.w * w3;
        }
    }
    for (int k4 = 0; k4 < 32; ++k4) {
        const float w0 = Wt[(128 + 4 * k4 + 0) * 65 + lane];
        const float w1 = Wt[(128 + 4 * k4 + 1) * 65 + lane];
        const float w2 = Wt[(128 + 4 * k4 + 2) * 65 + lane];
        const float w3 = Wt[(128 + 4 * k4 + 3) * 65 + lane];
#pragma unroll
        for (int r = 0; r < 8; ++r) {
            const int row = min(row0 + r, NN - 1);
            const float4 f = *(const float4*)(neigh + (size_t)row * DF + k4 * 4);
            acc[r] += f.x * w0 + f.y * w1 + f.z * w2 + f.w * w3;
        }
    }
#pragma unroll
    for (int r = 0; r < 8; ++r) {
        const int row = row0 + r;
        if (row < NN) out[(size_t)row * DF + oh * 64 + lane] = acc[r];
    }
}

extern "C" void kernel_launch(void* const* d_in, const int* in_sizes, int n_in,
                              void* d_out, int out_size, void* d_ws, size_t ws_size,
                              hipStream_t stream) {
    const float* feat  = (const float*)d_in[0];
    const float* W_src = (const float*)d_in[1];
    const float* b_src = (const float*)d_in[2];
    const float* W_fc  = (const float*)d_in[3];
    const float* b_fc  = (const float*)d_in[4];
    const int*   src   = (const int*)d_in[5];
    const int*   dst   = (const int*)d_in[6];
    float* out = (float*)d_out;

    // ws: feat_bf [NN*64 u32] | neigh [NN*128 f32] | deg [NN] | wprod [128*128] |
    //     bsrc2 [128] | off [NBUCK+1] | tbl [NTILES*NBUCK] | ents [NE u32]
    unsigned int* feat_bf = (unsigned int*)d_ws;
    float* neigh = (float*)(feat_bf + (size_t)NN * 64);
    int*   deg   = (int*)(neigh + (size_t)NN * DF);
    float* wprod = (float*)(deg + NN);
    float* bsrc2 = wprod + 128 * 128;
    int*   off   = (int*)(bsrc2 + 128);
    int*   tbl   = off + (NBUCK + 1);
    unsigned int* ents = (unsigned int*)(tbl + (size_t)NTILES * NBUCK);

    pack_feat  <<<(NN * 64 + 255) / 256, 256, 0, stream>>>(feat, feat_bf);
    prep_w     <<<128, 128, 0, stream>>>(W_fc, W_src, b_src, wprod, bsrc2);
    hist2      <<<NTILES, 1024, 0, stream>>>(dst, tbl);
    scan2      <<<1, 1024, 0, stream>>>(tbl, off);
    bin2       <<<NTILES, 1024, 0, stream>>>(src, dst, tbl, ents);
    gather_feat<<<NBUCK, 256, 0, stream>>>(feat_bf, ents, off, neigh, deg);
    apply_fc   <<<dim3((NN + 63) / 64, 2), 512, 0, stream>>>(feat, neigh, deg, W_fc,
                                                             wprod, b_fc, bsrc2, out);
}

// Round 9
// 100.742 us; speedup vs baseline: 10.1022x; 1.2794x over previous
//
#include <hip/hip_runtime.h>

#define NN 10000
#define DF 128
#define NE 640000
#define GBN 16                    // nodes per bucket
#define NBUCK 625                 // NN/16
#define TILE 8192
#define NTILES ((NE + TILE - 1) / TILE)   // 79
#define EPT 8                     // edges/thread in hist/bin (1024 thr)
#define GCAP 2048                 // bucket entry capacity (E=1024, sd~32)

#define PACK_BLKS 625             // NN*64 / 1024
#define PREP_BLKS 16              // 128 o-rows / 8

__device__ __forceinline__ unsigned int f2bf(float f) {
    unsigned int u = __float_as_uint(f);
    u = (u + 0x7FFFu + ((u >> 16) & 1u)) >> 16;   // RNE
    return u;
}
__device__ __forceinline__ float bf_lo(unsigned int v) { return __uint_as_float(v << 16); }
__device__ __forceinline__ float bf_hi(unsigned int v) { return __uint_as_float(v & 0xFFFF0000u); }

// ---------------------------------------------------------------------------
// P: fused prologue. blockIdx roles:
//   [0, 625)        : pack feat -> bf16 pairs (l, l+64) per u32
//   [625, 625+79)   : per-(tile,bucket) histogram -> tbl[t*NBUCK+b]
//   [704, 704+16)   : prep_w (wprod = Wfc2 @ W_src, bsrc2 = Wfc2 . b_src)
// ---------------------------------------------------------------------------
__global__ __launch_bounds__(1024) void prologue(const float* __restrict__ feat,
                                                 unsigned int* __restrict__ feat_bf,
                                                 const int* __restrict__ dstv,
                                                 int* __restrict__ tbl,
                                                 const float* __restrict__ Wfc,
                                                 const float* __restrict__ Wsrc,
                                                 const float* __restrict__ bsrc,
                                                 float* __restrict__ wprod,
                                                 float* __restrict__ bsrc2)
{
    const int bx = blockIdx.x, tid = threadIdx.x;

    if (bx < PACK_BLKS) {
        const int id = bx * 1024 + tid;          // < NN*64 = 640000 exactly
        const int row = id >> 6, l = id & 63;
        feat_bf[id] = f2bf(feat[row * DF + l]) | (f2bf(feat[row * DF + l + 64]) << 16);
        return;
    }
    if (bx < PACK_BLKS + NTILES) {
        __shared__ int h[NBUCK];
        const int t = bx - PACK_BLKS;
        if (tid < NBUCK) h[tid] = 0;
        __syncthreads();
        const int e0 = t * TILE;
#pragma unroll
        for (int j = 0; j < EPT; ++j) {
            const int e = e0 + j * 1024 + tid;
            if (e < NE) atomicAdd(&h[dstv[e] >> 4], 1);
        }
        __syncthreads();
        if (tid < NBUCK) tbl[t * NBUCK + tid] = h[tid];
        return;
    }
    {   // prep: 16 blocks x 8 output rows; group g = 128 threads (2 waves)
        __shared__ float red[16];
        const int g = tid >> 7;                 // 0..7
        const int k = tid & 127;
        const int o = (bx - PACK_BLKS - NTILES) * 8 + g;
        const float* w2 = Wfc + (size_t)o * 256 + 128;   // uniform -> s_load
        float acc = 0.f;
#pragma unroll 8
        for (int j = 0; j < 128; ++j)
            acc = fmaf(w2[j], Wsrc[j * 128 + k], acc);
        wprod[o * 128 + k] = acc;

        float p = w2[k] * bsrc[k];
#pragma unroll
        for (int d = 32; d > 0; d >>= 1) p += __shfl_down(p, d);
        const int wv = tid >> 6;
        if ((tid & 63) == 0) red[wv] = p;
        __syncthreads();
        if (k == 0) bsrc2[o] = red[2 * g] + red[2 * g + 1];
    }
}

// ---------------------------------------------------------------------------
// B2: in-place: tbl[t][b] = off[b] + sum_{t'<t} h[t'][b]. Deterministic.
// ---------------------------------------------------------------------------
__global__ __launch_bounds__(1024) void scan2(int* __restrict__ tbl,
                                              int* __restrict__ off)
{
    __shared__ int sc[1024];
    const int b = threadIdx.x;
    int tot = 0;
    if (b < NBUCK) {
        for (int t = 0; t < NTILES; ++t) {
            const int c = tbl[t * NBUCK + b];
            tbl[t * NBUCK + b] = tot;
            tot += c;
        }
    }
    sc[b] = (b < NBUCK) ? tot : 0;
    __syncthreads();
    for (int d = 1; d < 1024; d <<= 1) {
        int x = (b >= d) ? sc[b - d] : 0;
        __syncthreads();
        sc[b] += x;
        __syncthreads();
    }
    if (b < NBUCK) {
        const int base = (b == 0) ? 0 : sc[b - 1];
        off[b] = base;
        for (int t = 0; t < NTILES; ++t) tbl[t * NBUCK + b] += base;
    }
    if (b == NBUCK - 1) off[NBUCK] = sc[b];
}

// ---------------------------------------------------------------------------
// B3: LDS-staged binning with PRECOMPUTED bases (no global atomics,
// deterministic, replay-safe). entry = (dst<<14)|src; bucket = entry>>18.
// ---------------------------------------------------------------------------
__global__ __launch_bounds__(1024) void bin2(const int* __restrict__ srcv,
                                             const int* __restrict__ dstv,
                                             const int* __restrict__ tbl,
                                             unsigned int* __restrict__ ents)
{
    __shared__ unsigned int ent[TILE];   // 32 KB
    __shared__ int h[NBUCK];
    __shared__ int lbase[NBUCK];
    __shared__ int lcur[NBUCK];
    __shared__ int gbase[NBUCK];
    __shared__ int sc[1024];

    const int tid = threadIdx.x;
    const int bx = blockIdx.x;
    const int e0 = bx * TILE;
    const int n = min(TILE, NE - e0);

    int myd[EPT], mys[EPT];
#pragma unroll
    for (int j = 0; j < EPT; ++j) {
        const int e = e0 + j * 1024 + tid;
        if (e < NE) { myd[j] = dstv[e]; mys[j] = srcv[e]; }
        else { myd[j] = -1; mys[j] = 0; }
    }

    if (tid < NBUCK) {
        h[tid] = 0; lcur[tid] = 0;
        gbase[tid] = tbl[bx * NBUCK + tid];   // deterministic global base
    }
    __syncthreads();
#pragma unroll
    for (int j = 0; j < EPT; ++j)
        if (myd[j] >= 0) atomicAdd(&h[myd[j] >> 4], 1);
    __syncthreads();

    sc[tid] = (tid < NBUCK) ? h[tid] : 0;
    __syncthreads();
    for (int d = 1; d < 1024; d <<= 1) {
        int x = (tid >= d) ? sc[tid - d] : 0;
        __syncthreads();
        sc[tid] += x;
        __syncthreads();
    }
    if (tid < NBUCK) lbase[tid] = (tid == 0) ? 0 : sc[tid - 1];
    __syncthreads();

    // local scatter into bucket-sorted LDS order (int LDS atomics only)
#pragma unroll
    for (int j = 0; j < EPT; ++j) {
        if (myd[j] >= 0) {
            const int b = myd[j] >> 4;
            const int p = atomicAdd(&lcur[b], 1);
            ent[lbase[b] + p] = ((unsigned)myd[j] << 14) | (unsigned)mys[j];
        }
    }
    __syncthreads();

    // coalesced flush into disjoint precomputed global runs
    for (int i = tid; i < n; i += 1024) {
        const unsigned u = ent[i];
        const int b = (int)(u >> 18);        // dst>>4
        ents[gbase[b] + (i - lbase[b])] = u;
    }
}

// ---------------------------------------------------------------------------
// G: one block per 16-node bucket. Counting-sort entries by local dst in
// LDS (int atomics only), then 4 waves x 4 nodes with REGISTER accumulation,
// 4-deep independent 256B gathers. Zero f32 atomics.
// ---------------------------------------------------------------------------
__global__ __launch_bounds__(256) void gather_feat(const unsigned int* __restrict__ feat_bf,
                                                   const unsigned int* __restrict__ ents,
                                                   const int* __restrict__ off,
                                                   float* __restrict__ neigh,
                                                   int* __restrict__ deg_g)
{
    __shared__ unsigned int raw[GCAP];       // 8 KB
    __shared__ unsigned short sorted[GCAP];  // 4 KB
    __shared__ int h[GBN], base[GBN], cur[GBN];

    const int tid = threadIdx.x;
    const int b = blockIdx.x;
    const int lo = b * GBN;
    const int r0 = off[b], r1 = off[b + 1];
    const int cnt = min(r1 - r0, GCAP);

    if (tid < GBN) { h[tid] = 0; cur[tid] = 0; }
    __syncthreads();
    for (int i = tid; i < cnt; i += 256) {
        const unsigned u = ents[r0 + i];
        raw[i] = u;
        atomicAdd(&h[(u >> 14) & (GBN - 1)], 1);
    }
    __syncthreads();
    if (tid == 0) {
        int s = 0;
#pragma unroll
        for (int j = 0; j < GBN; ++j) { base[j] = s; s += h[j]; }
    }
    __syncthreads();
    for (int i = tid; i < cnt; i += 256) {
        const unsigned u = raw[i];
        const int dl = (int)((u >> 14) & (GBN - 1));
        const int p = base[dl] + atomicAdd(&cur[dl], 1);
        sorted[p] = (unsigned short)(u & 0x3FFFu);
    }
    __syncthreads();

    const int wave = tid >> 6, lane = tid & 63;
#pragma unroll
    for (int j = 0; j < 4; ++j) {
        const int dl = wave * 4 + j;
        const int s0 = base[dl], n = h[dl];
        float ax = 0.f, ay = 0.f;
        int i = 0;
        for (; i + 4 <= n; i += 4) {
            const int ia = sorted[s0 + i + 0];
            const int ib = sorted[s0 + i + 1];
            const int ic = sorted[s0 + i + 2];
            const int id = sorted[s0 + i + 3];
            const unsigned a  = feat_bf[(size_t)ia * 64 + lane];
            const unsigned bb = feat_bf[(size_t)ib * 64 + lane];
            const unsigned c  = feat_bf[(size_t)ic * 64 + lane];
            const unsigned d  = feat_bf[(size_t)id * 64 + lane];
            ax += (bf_lo(a) + bf_lo(bb)) + (bf_lo(c) + bf_lo(d));
            ay += (bf_hi(a) + bf_hi(bb)) + (bf_hi(c) + bf_hi(d));
        }
        for (; i < n; ++i) {
            const unsigned a = feat_bf[(size_t)sorted[s0 + i] * 64 + lane];
            ax += bf_lo(a); ay += bf_hi(a);
        }
        const int v = lo + dl;
        const float inv = (n > 0) ? 1.f / (float)n : 0.f;
        if (v < NN) {
            neigh[(size_t)v * DF + lane]      = ax * inv;
            neigh[(size_t)v * DF + 64 + lane] = ay * inv;
            if (lane == 0) deg_g[v] = n;
        }
    }
}

// ---------------------------------------------------------------------------
// A v2: out = feat @ Wfc1^T + neigh @ wprod^T + b_fc + [deg>0]*bsrc2
// Lane = row (per-lane float4 row loads), 8 out cols per thread
// (blockIdx.y picks the 8-col tile). Weights are wave-uniform -> s_load
// (SGPR operand, scalar-cache). No LDS, no barriers, 1-wave blocks,
// grid (157,16) = 2512 waves (~2.45/SIMD).
// ---------------------------------------------------------------------------
__global__ __launch_bounds__(64) void apply_fc(const float* __restrict__ feat,
                                               const float* __restrict__ neigh,
                                               const int* __restrict__ deg,
                                               const float* __restrict__ Wfc,
                                               const float* __restrict__ wprod,
                                               const float* __restrict__ bfc,
                                               const float* __restrict__ bsrc2,
                                               float* __restrict__ out)
{
    const int row = blockIdx.x * 64 + threadIdx.x;
    if (row >= NN) return;
    const int ob = blockIdx.y * 8;

    const bool hasdeg = deg[row] > 0;
    float acc[8];
#pragma unroll
    for (int o = 0; o < 8; ++o)
        acc[o] = bfc[ob + o] + (hasdeg ? bsrc2[ob + o] : 0.0f);

    const float4* f4 = (const float4*)(feat + (size_t)row * DF);
    const float4* n4 = (const float4*)(neigh + (size_t)row * DF);
#pragma unroll 4
    for (int k4 = 0; k4 < 32; ++k4) {
        const float4 f = f4[k4];
        const float4 nn = n4[k4];
#pragma unroll
        for (int o = 0; o < 8; ++o) {
            const float* w1 = Wfc + (size_t)(ob + o) * 256 + k4 * 4;     // uniform
            const float* w2 = wprod + (size_t)(ob + o) * 128 + k4 * 4;   // uniform
            acc[o] += f.x * w1[0] + f.y * w1[1] + f.z * w1[2] + f.w * w1[3]
                    + nn.x * w2[0] + nn.y * w2[1] + nn.z * w2[2] + nn.w * w2[3];
        }
    }
    float* orow = out + (size_t)row * DF + ob;
    *(float4*)(orow)     = make_float4(acc[0], acc[1], acc[2], acc[3]);
    *(float4*)(orow + 4) = make_float4(acc[4], acc[5], acc[6], acc[7]);
}

extern "C" void kernel_launch(void* const* d_in, const int* in_sizes, int n_in,
                              void* d_out, int out_size, void* d_ws, size_t ws_size,
                              hipStream_t stream) {
    const float* feat  = (const float*)d_in[0];
    const float* W_src = (const float*)d_in[1];
    const float* b_src = (const float*)d_in[2];
    const float* W_fc  = (const float*)d_in[3];
    const float* b_fc  = (const float*)d_in[4];
    const int*   src   = (const int*)d_in[5];
    const int*   dst   = (const int*)d_in[6];
    float* out = (float*)d_out;

    // ws: feat_bf [NN*64 u32] | neigh [NN*128 f32] | deg [NN] | wprod [128*128] |
    //     bsrc2 [128] | off [NBUCK+1] | tbl [NTILES*NBUCK] | ents [NE u32]
    unsigned int* feat_bf = (unsigned int*)d_ws;
    float* neigh = (float*)(feat_bf + (size_t)NN * 64);
    int*   deg   = (int*)(neigh + (size_t)NN * DF);
    float* wprod = (float*)(deg + NN);
    float* bsrc2 = wprod + 128 * 128;
    int*   off   = (int*)(bsrc2 + 128);
    int*   tbl   = off + (NBUCK + 1);
    unsigned int* ents = (unsigned int*)(tbl + (size_t)NTILES * NBUCK);

    prologue   <<<PACK_BLKS + NTILES + PREP_BLKS, 1024, 0, stream>>>(
                   feat, feat_bf, dst, tbl, W_fc, W_src, b_src, wprod, bsrc2);
    scan2      <<<1, 1024, 0, stream>>>(tbl, off);
    bin2       <<<NTILES, 1024, 0, stream>>>(src, dst, tbl, ents);
    gather_feat<<<NBUCK, 256, 0, stream>>>(feat_bf, ents, off, neigh, deg);
    apply_fc   <<<dim3((NN + 63) / 64, 16), 64, 0, stream>>>(feat, neigh, deg, W_fc,
                                                             wprod, b_fc, bsrc2, out);
}

// Round 10
// 73.198 us; speedup vs baseline: 13.9036x; 1.3763x over previous
//
#include <hip/hip_runtime.h>

#define NN 10000
#define DF 128
#define NE 640000
#define GBN 16                    // nodes per bucket
#define NBUCK 625                 // NN/16
#define TILE 8192
#define NTILES ((NE + TILE - 1) / TILE)   // 79
#define EPT 8                     // edges/thread in hist/bin (1024 thr)
#define GCAP 2048                 // bucket entry capacity (E=1024, sd~32)

#define PACK_BLKS 625             // NN*64 / 1024
#define PREP_BLKS 16              // 128 o-rows / 8

typedef __attribute__((ext_vector_type(8))) short bf16x8;
typedef __attribute__((ext_vector_type(4))) float f32x4;

__device__ __forceinline__ unsigned int f2bf(float f) {
    unsigned int u = __float_as_uint(f);
    u = (u + 0x7FFFu + ((u >> 16) & 1u)) >> 16;   // RNE
    return u;
}
__device__ __forceinline__ unsigned int pack2bf(float a, float b) {
    return f2bf(a) | (f2bf(b) << 16);
}
__device__ __forceinline__ float bf_lo(unsigned int v) { return __uint_as_float(v << 16); }
__device__ __forceinline__ float bf_hi(unsigned int v) { return __uint_as_float(v & 0xFFFF0000u); }

// ---------------------------------------------------------------------------
// P: fused prologue. blockIdx roles:
//   [0, 625)      : pack feat -> A_bf[row][0:64] u32 pairs (k=2j, 2j+1 linear)
//   [625, 704)    : per-(tile,bucket) histogram -> tbl[t*NBUCK+b]
//   [704, 720)    : prep: wprod = Wfc2 @ W_src (LDS), pack Bw bf16, bsrc2
// ---------------------------------------------------------------------------
__global__ __launch_bounds__(1024) void prologue(const float* __restrict__ feat,
                                                 unsigned int* __restrict__ A_bf,
                                                 const int* __restrict__ dstv,
                                                 int* __restrict__ tbl,
                                                 const float* __restrict__ Wfc,
                                                 const float* __restrict__ Wsrc,
                                                 const float* __restrict__ bsrc,
                                                 unsigned int* __restrict__ Bw,
                                                 float* __restrict__ bsrc2)
{
    const int bx = blockIdx.x, tid = threadIdx.x;

    if (bx < PACK_BLKS) {
        const int id = bx * 1024 + tid;          // < NN*64
        const int row = id >> 6, j = id & 63;
        const float2 f = *(const float2*)(feat + (size_t)row * DF + 2 * j);
        A_bf[(size_t)row * 128 + j] = pack2bf(f.x, f.y);
        return;
    }
    if (bx < PACK_BLKS + NTILES) {
        __shared__ int h[NBUCK];
        const int t = bx - PACK_BLKS;
        if (tid < NBUCK) h[tid] = 0;
        __syncthreads();
        const int e0 = t * TILE;
#pragma unroll
        for (int j = 0; j < EPT; ++j) {
            const int e = e0 + j * 1024 + tid;
            if (e < NE) atomicAdd(&h[dstv[e] >> 4], 1);
        }
        __syncthreads();
        if (tid < NBUCK) tbl[t * NBUCK + tid] = h[tid];
        return;
    }
    {   // prep: 16 blocks x 8 output rows; group g = 128 threads
        __shared__ float wp[8][128];
        __shared__ float red[16];
        const int g = tid >> 7;                 // 0..7
        const int k = tid & 127;
        const int o = (bx - PACK_BLKS - NTILES) * 8 + g;
        const float* w2 = Wfc + (size_t)o * 256 + 128;   // uniform -> s_load
        float acc = 0.f;
#pragma unroll 8
        for (int j = 0; j < 128; ++j)
            acc = fmaf(w2[j], Wsrc[j * 128 + k], acc);
        wp[g][k] = acc;

        float p = w2[k] * bsrc[k];
#pragma unroll
        for (int d = 32; d > 0; d >>= 1) p += __shfl_down(p, d);
        if ((tid & 63) == 0) red[tid >> 6] = p;
        __syncthreads();
        if (k < 64) {
            // Wfc1 half: Bw[o][0:64]
            const float2 wf = *(const float2*)(Wfc + (size_t)o * 256 + 2 * k);
            Bw[(size_t)o * 128 + k] = pack2bf(wf.x, wf.y);
            // wprod half: Bw[o][64:128]
            Bw[(size_t)o * 128 + 64 + k] = pack2bf(wp[g][2 * k], wp[g][2 * k + 1]);
        }
        if (k == 0) bsrc2[o] = red[2 * g] + red[2 * g + 1];
    }
}

// ---------------------------------------------------------------------------
// B2: in-place: tbl[t][b] = off[b] + sum_{t'<t} h[t'][b]. Deterministic.
// ---------------------------------------------------------------------------
__global__ __launch_bounds__(1024) void scan2(int* __restrict__ tbl,
                                              int* __restrict__ off)
{
    __shared__ int sc[1024];
    const int b = threadIdx.x;
    int tot = 0;
    if (b < NBUCK) {
        for (int t = 0; t < NTILES; ++t) {
            const int c = tbl[t * NBUCK + b];
            tbl[t * NBUCK + b] = tot;
            tot += c;
        }
    }
    sc[b] = (b < NBUCK) ? tot : 0;
    __syncthreads();
    for (int d = 1; d < 1024; d <<= 1) {
        int x = (b >= d) ? sc[b - d] : 0;
        __syncthreads();
        sc[b] += x;
        __syncthreads();
    }
    if (b < NBUCK) {
        const int base = (b == 0) ? 0 : sc[b - 1];
        off[b] = base;
        for (int t = 0; t < NTILES; ++t) tbl[t * NBUCK + b] += base;
    }
    if (b == NBUCK - 1) off[NBUCK] = sc[b];
}

// ---------------------------------------------------------------------------
// B3: LDS-staged binning with PRECOMPUTED bases (no global atomics,
// deterministic, replay-safe). entry = (dst<<14)|src; bucket = entry>>18.
// ---------------------------------------------------------------------------
__global__ __launch_bounds__(1024) void bin2(const int* __restrict__ srcv,
                                             const int* __restrict__ dstv,
                                             const int* __restrict__ tbl,
                                             unsigned int* __restrict__ ents)
{
    __shared__ unsigned int ent[TILE];   // 32 KB
    __shared__ int h[NBUCK];
    __shared__ int lbase[NBUCK];
    __shared__ int lcur[NBUCK];
    __shared__ int gbase[NBUCK];
    __shared__ int sc[1024];

    const int tid = threadIdx.x;
    const int bx = blockIdx.x;
    const int e0 = bx * TILE;
    const int n = min(TILE, NE - e0);

    int myd[EPT], mys[EPT];
#pragma unroll
    for (int j = 0; j < EPT; ++j) {
        const int e = e0 + j * 1024 + tid;
        if (e < NE) { myd[j] = dstv[e]; mys[j] = srcv[e]; }
        else { myd[j] = -1; mys[j] = 0; }
    }

    if (tid < NBUCK) {
        h[tid] = 0; lcur[tid] = 0;
        gbase[tid] = tbl[bx * NBUCK + tid];   // deterministic global base
    }
    __syncthreads();
#pragma unroll
    for (int j = 0; j < EPT; ++j)
        if (myd[j] >= 0) atomicAdd(&h[myd[j] >> 4], 1);
    __syncthreads();

    sc[tid] = (tid < NBUCK) ? h[tid] : 0;
    __syncthreads();
    for (int d = 1; d < 1024; d <<= 1) {
        int x = (tid >= d) ? sc[tid - d] : 0;
        __syncthreads();
        sc[tid] += x;
        __syncthreads();
    }
    if (tid < NBUCK) lbase[tid] = (tid == 0) ? 0 : sc[tid - 1];
    __syncthreads();

    // local scatter into bucket-sorted LDS order (int LDS atomics only)
#pragma unroll
    for (int j = 0; j < EPT; ++j) {
        if (myd[j] >= 0) {
            const int b = myd[j] >> 4;
            const int p = atomicAdd(&lcur[b], 1);
            ent[lbase[b] + p] = ((unsigned)myd[j] << 14) | (unsigned)mys[j];
        }
    }
    __syncthreads();

    // coalesced flush into disjoint precomputed global runs
    for (int i = tid; i < n; i += 1024) {
        const unsigned u = ent[i];
        const int b = (int)(u >> 18);        // dst>>4
        ents[gbase[b] + (i - lbase[b])] = u;
    }
}

// ---------------------------------------------------------------------------
// G: one block per 16-node bucket. Counting-sort entries by local dst in LDS
// (int atomics only), then 4 waves x 4 nodes with REGISTER accumulation.
// Writes the mean directly as bf16 pairs into A_bf[v][64:128] + deg.
// ---------------------------------------------------------------------------
__global__ __launch_bounds__(256) void gather_feat(unsigned int* __restrict__ A_bf,
                                                   const unsigned int* __restrict__ ents,
                                                   const int* __restrict__ off,
                                                   int* __restrict__ deg_g)
{
    __shared__ unsigned int raw[GCAP];       // 8 KB
    __shared__ unsigned short sorted[GCAP];  // 4 KB
    __shared__ int h[GBN], base[GBN], cur[GBN];

    const int tid = threadIdx.x;
    const int b = blockIdx.x;
    const int lo = b * GBN;
    const int r0 = off[b], r1 = off[b + 1];
    const int cnt = min(r1 - r0, GCAP);

    if (tid < GBN) { h[tid] = 0; cur[tid] = 0; }
    __syncthreads();
    for (int i = tid; i < cnt; i += 256) {
        const unsigned u = ents[r0 + i];
        raw[i] = u;
        atomicAdd(&h[(u >> 14) & (GBN - 1)], 1);
    }
    __syncthreads();
    if (tid == 0) {
        int s = 0;
#pragma unroll
        for (int j = 0; j < GBN; ++j) { base[j] = s; s += h[j]; }
    }
    __syncthreads();
    for (int i = tid; i < cnt; i += 256) {
        const unsigned u = raw[i];
        const int dl = (int)((u >> 14) & (GBN - 1));
        const int p = base[dl] + atomicAdd(&cur[dl], 1);
        sorted[p] = (unsigned short)(u & 0x3FFFu);
    }
    __syncthreads();

    const int wave = tid >> 6, lane = tid & 63;
#pragma unroll
    for (int j = 0; j < 4; ++j) {
        const int dl = wave * 4 + j;
        const int s0 = base[dl], n = h[dl];
        float ax = 0.f, ay = 0.f;
        int i = 0;
        for (; i + 4 <= n; i += 4) {
            const int ia = sorted[s0 + i + 0];
            const int ib = sorted[s0 + i + 1];
            const int ic = sorted[s0 + i + 2];
            const int id = sorted[s0 + i + 3];
            const unsigned a  = A_bf[(size_t)ia * 128 + lane];
            const unsigned bb = A_bf[(size_t)ib * 128 + lane];
            const unsigned c  = A_bf[(size_t)ic * 128 + lane];
            const unsigned d  = A_bf[(size_t)id * 128 + lane];
            ax += (bf_lo(a) + bf_lo(bb)) + (bf_lo(c) + bf_lo(d));
            ay += (bf_hi(a) + bf_hi(bb)) + (bf_hi(c) + bf_hi(d));
        }
        for (; i < n; ++i) {
            const unsigned a = A_bf[(size_t)sorted[s0 + i] * 128 + lane];
            ax += bf_lo(a); ay += bf_hi(a);
        }
        const int v = lo + dl;
        const float inv = (n > 0) ? 1.f / (float)n : 0.f;
        if (v < NN) {
            A_bf[(size_t)v * 128 + 64 + lane] = pack2bf(ax * inv, ay * inv);
            if (lane == 0) deg_g[v] = n;
        }
    }
}

// ---------------------------------------------------------------------------
// A v3 (MFMA): out = A_bf @ Bw^T + b_fc + [deg>0]*bsrc2
// A_bf [10000][256] bf16 row-major, Bw [128][256] bf16 row-major.
// One wave per 16x16 output tile; K=256 -> 8x mfma_f32_16x16x32_bf16.
// Fragments load straight from row-major global (16B/lane, L2-resident):
//   a: A[rbase+(l&15)][(l>>4)*8+..]   b: Bw[cbase+(l&15)][(l>>4)*8+..]
// D mapping (m89-verified): col = lane&15, row = (lane>>4)*4 + reg.
// Grid (625, 8) = 5000 waves (~4.9/SIMD).
// ---------------------------------------------------------------------------
__global__ __launch_bounds__(64) void apply_mfma(const unsigned int* __restrict__ A_bf,
                                                 const unsigned int* __restrict__ Bw,
                                                 const int* __restrict__ deg,
                                                 const float* __restrict__ bfc,
                                                 const float* __restrict__ bsrc2,
                                                 float* __restrict__ out)
{
    const int lane = threadIdx.x;
    const int rbase = blockIdx.x * 16;
    const int cbase = blockIdx.y * 16;
    const int r = lane & 15, kg = lane >> 4;

    const unsigned int* ap = A_bf + (size_t)(rbase + r) * 128 + kg * 4;
    const unsigned int* bp = Bw   + (size_t)(cbase + r) * 128 + kg * 4;

    bf16x8 a[8], b[8];
#pragma unroll
    for (int s = 0; s < 8; ++s) {
        a[s] = *(const bf16x8*)(ap + s * 16);
        b[s] = *(const bf16x8*)(bp + s * 16);
    }
    f32x4 acc = {0.f, 0.f, 0.f, 0.f};
#pragma unroll
    for (int s = 0; s < 8; ++s)
        acc = __builtin_amdgcn_mfma_f32_16x16x32_bf16(a[s], b[s], acc, 0, 0, 0);

    const int col = cbase + r;
    const float bc = bfc[col], bs = bsrc2[col];
#pragma unroll
    for (int q = 0; q < 4; ++q) {
        const int row = rbase + kg * 4 + q;
        out[(size_t)row * DF + col] = acc[q] + bc + (deg[row] > 0 ? bs : 0.f);
    }
}

extern "C" void kernel_launch(void* const* d_in, const int* in_sizes, int n_in,
                              void* d_out, int out_size, void* d_ws, size_t ws_size,
                              hipStream_t stream) {
    const float* feat  = (const float*)d_in[0];
    const float* W_src = (const float*)d_in[1];
    const float* b_src = (const float*)d_in[2];
    const float* W_fc  = (const float*)d_in[3];
    const float* b_fc  = (const float*)d_in[4];
    const int*   src   = (const int*)d_in[5];
    const int*   dst   = (const int*)d_in[6];
    float* out = (float*)d_out;

    // ws: A_bf [NN*128 u32] | deg [NN] | Bw [128*128 u32] | bsrc2 [128 f32] |
    //     off [NBUCK+1] | tbl [NTILES*NBUCK] | ents [NE u32]
    unsigned int* A_bf = (unsigned int*)d_ws;
    int*   deg   = (int*)(A_bf + (size_t)NN * 128);
    unsigned int* Bw = (unsigned int*)(deg + NN);
    float* bsrc2 = (float*)(Bw + 128 * 128);
    int*   off   = (int*)(bsrc2 + 128);
    int*   tbl   = off + (NBUCK + 1);
    unsigned int* ents = (unsigned int*)(tbl + (size_t)NTILES * NBUCK);

    prologue   <<<PACK_BLKS + NTILES + PREP_BLKS, 1024, 0, stream>>>(
                   feat, A_bf, dst, tbl, W_fc, W_src, b_src, Bw, bsrc2);
    scan2      <<<1, 1024, 0, stream>>>(tbl, off);
    bin2       <<<NTILES, 1024, 0, stream>>>(src, dst, tbl, ents);
    gather_feat<<<NBUCK, 256, 0, stream>>>(A_bf, ents, off, deg);
    apply_mfma <<<dim3(NN / 16, 8), 64, 0, stream>>>(A_bf, Bw, deg, b_fc, bsrc2, out);
}